// Round 10
// baseline (347.522 us; speedup 1.0000x reference)
//
#include <hip/hip_runtime.h>
#include <hip/hip_bf16.h>

#define B_  8
#define D_  128
#define K_  7
#define Q_  256
#define G0_ 511
#define G0P 512
#define G1_ 512
#define F1_ 512
#define F2_ 1024
#define OUT_ 16

typedef __bf16 bf16x8 __attribute__((ext_vector_type(8)));
typedef float  f32x4  __attribute__((ext_vector_type(4)));

// async global->LDS: one instruction = 64 lanes x 16B = 1KB.
#define GL2LDS(g, l) __builtin_amdgcn_global_load_lds(                        \
    (const __attribute__((address_space(1))) void*)(g),                       \
    (__attribute__((address_space(3))) void*)(l), 16, 0, 0)

// ---------------------------------------------------------------------------
// Device-scope generation barrier. bar[0]=count, bar[1]=generation.
// All 512 blocks are co-resident (LDS: 3/CU; launch_bounds(256,2): 2/CU;
// grid = 2 x 256 CUs exactly), so spinning is safe.
__device__ __forceinline__ void gbar(int* bar, int nblk) {
    __syncthreads();
    if (threadIdx.x == 0) {
        __threadfence();   // make this block's writes device-visible
        const int g = __hip_atomic_load(&bar[1], __ATOMIC_ACQUIRE,
                                        __HIP_MEMORY_SCOPE_AGENT);
        const int prev = __hip_atomic_fetch_add(&bar[0], 1, __ATOMIC_ACQ_REL,
                                                __HIP_MEMORY_SCOPE_AGENT);
        if (prev == nblk - 1) {
            __hip_atomic_store(&bar[0], 0, __ATOMIC_RELAXED,
                               __HIP_MEMORY_SCOPE_AGENT);
            __hip_atomic_fetch_add(&bar[1], 1, __ATOMIC_RELEASE,
                                   __HIP_MEMORY_SCOPE_AGENT);
        } else {
            while (__hip_atomic_load(&bar[1], __ATOMIC_ACQUIRE,
                                     __HIP_MEMORY_SCOPE_AGENT) == g)
                __builtin_amdgcn_s_sleep(2);
        }
        __threadfence();
    }
    __syncthreads();
}

// ---------------------------------------------------------------------------
// k_prep: fused preprocessing, 1320 blocks x 256 threads. (all R3-verified)
__global__ void k_prep(const float* __restrict__ x, const float* __restrict__ g0w,
                       const float* __restrict__ g0b, const float* __restrict__ qst,
                       const float* __restrict__ g1w, const float* __restrict__ g1b,
                       float* __restrict__ u, float* __restrict__ v,
                       __bf16* __restrict__ w1t, float* __restrict__ qterm,
                       float* __restrict__ xg) {
    const int blk = blockIdx.x;
    const int t   = threadIdx.x;
    if (blk < 1024) {
        __shared__ float xs[8];
        if (t < K_) xs[t] = x[blk * K_ + t];
        __syncthreads();
        #pragma unroll
        for (int h = 0; h < 2; ++h) {
            const int g = t + h * 256;
            float su = 0.f, sv = 0.f;
            if (g < G0_) {
                #pragma unroll
                for (int k = 0; k < K_; ++k) {
                    su += xs[k] * g0w[k * G0_ + g];
                    sv += xs[k] * g0w[(K_ + k) * G0_ + g];
                }
                su += g0b[g];
            }
            u[blk * G0P + g] = (g < G0_) ? su : 0.f;
            v[blk * G0P + g] = (g < G0_) ? sv : 0.f;
        }
    } else if (blk < 1280) {
        // w1t[kq*16384 + n*32 + slot*8 + j], slot = chunk^((n>>1)&3)
        __shared__ __bf16 tile[32][33];
        const int bb = blk - 1024;
        const int bx = bb & 15, by = bb >> 4;
        const int r = t >> 5, c = t & 31;
        #pragma unroll
        for (int i = 0; i < 4; ++i) {
            const int k = by * 32 + r + i * 8;
            const int n = bx * 32 + c;
            tile[r + i * 8][c] = (__bf16)((k < G0_) ? g1w[k * G1_ + n] : 0.f);
        }
        __syncthreads();
        #pragma unroll
        for (int i = 0; i < 4; ++i) {
            const int n = bx * 32 + r + i * 8;
            const int cc = (c >> 3) & 3, j = c & 7;
            const int slot = cc ^ ((n >> 1) & 3);
            w1t[by * 16384 + n * 32 + slot * 8 + j] = tile[c][r + i * 8];
        }
    } else if (blk < 1312) {
        __shared__ float qs[256];
        __shared__ float red[2][128];
        const int qb = blk - 1280;
        const int b = qb >> 2, nb = (qb & 3) << 7;
        qs[t] = qst[b * Q_ + t];
        __syncthreads();
        const int n = nb + (t & 127);
        const int qh = (t >> 7) * 128;
        float s = 0.f;
        #pragma unroll 8
        for (int q = 0; q < 128; ++q)
            s += qs[qh + q] * g1w[(G0_ + qh + q) * G1_ + n];
        red[t >> 7][t & 127] = s;
        __syncthreads();
        if (t < 128)
            qterm[b * G1_ + nb + t] = red[0][t] + red[1][t] + g1b[nb + t];
    } else {
        const int b = blk - 1312;
        xg[b * G1_ + t] = 0.f;
        xg[b * G1_ + 256 + t] = 0.f;
    }
}

// ---------------------------------------------------------------------------
// k_main: pair GEMM (4 R3-verified units/block) -> gbar -> f1+f2 -> gbar -> f3.
// 512 blocks x 256 threads, all co-resident.
__global__ __launch_bounds__(256, 2)
void k_main(const float* __restrict__ u, const float* __restrict__ v,
            const __bf16* __restrict__ w1t, const float* __restrict__ qterm,
            const float* __restrict__ f1w, const float* __restrict__ f1b,
            const float* __restrict__ f2w, const float* __restrict__ f2b,
            const float* __restrict__ f3w, const float* __restrict__ f3b,
            float* __restrict__ xg, float* __restrict__ s2g,
            float* __restrict__ out, int* __restrict__ bar) {
    __shared__ float  v_a[512];        // 2 KB
    __shared__ __bf16 At[2][4096];     // 16 KB  [buf][mtile(8)][lane*8]
    __shared__ __bf16 Bt[2][8192];     // 32 KB  [buf][n_local(256)][32]
    __shared__ float  ebuf[4][128];    // 2 KB

    const int blk = blockIdx.x;        // [0,512)
    const int t   = threadIdx.x;
    const int nblk = gridDim.x;

    // ---------------- Phase 1: pair GEMM (R3-verified body) ----------------
    {
        const int wave = t >> 6, lane = t & 63;
        const int quad = lane >> 4, l15 = lane & 15;
        const int nloc = (wave >> 1) * 128;
        const int mtg  = (wave & 1) * 4;
        const int swz  = (l15 >> 1) & 3;
        const int iw0  = wave * 4;
        const int sm = t >> 1;
        const int sk = (t & 1) << 4;
        const int woff = (sm >> 4) * 512 + (sk >> 3) * 128 + (sm & 15) * 8;

        for (int i = 0; i < 4; ++i) {
            const int bid  = blk * 4 + i;
            const int b    = bid >> 8;
            const int a    = (bid >> 1) & 127;
            const int nbase = (bid & 1) << 8;

            __syncthreads();           // protect LDS across units
            if (t < 128)
                *(float4*)(v_a + t * 4) =
                    *(const float4*)(v + (b * D_ + a) * G0P + t * 4);

            const __bf16* gsrc = w1t + (size_t)(nbase + iw0 * 16 + (lane >> 2)) * 32
                                     + (lane & 3) * 8;
            const float* urow = u + (b * D_ + sm) * G0P + sk;

            f32x4 acc[4][8];
            #pragma unroll
            for (int mt = 0; mt < 4; ++mt)
                #pragma unroll
                for (int nt = 0; nt < 8; ++nt)
                    acc[mt][nt] = (f32x4){0.f, 0.f, 0.f, 0.f};

            float4 u0, u1, u2, u3;
            auto load_u = [&](int kq) {
                const float* p = urow + kq * 32;
                u0 = *(const float4*)p;       u1 = *(const float4*)(p + 4);
                u2 = *(const float4*)(p + 8); u3 = *(const float4*)(p + 12);
            };
            auto stage_B = [&](int buf, int kq) {
                const __bf16* g = gsrc + kq * 16384;
                __bf16* l = &Bt[buf][iw0 * 512];
                #pragma unroll
                for (int j = 0; j < 4; ++j)
                    GL2LDS(g + j * 512, l + j * 512);
            };
            auto write_A = [&](int buf, int kq) {
                const float* vp = v_a + kq * 32 + sk;
                const float4 v0 = *(const float4*)vp,       v1 = *(const float4*)(vp + 4);
                const float4 v2 = *(const float4*)(vp + 8), v3 = *(const float4*)(vp + 12);
                bf16x8 h0, h1;
                h0[0] = (__bf16)fmaxf(u0.x + v0.x, 0.f);
                h0[1] = (__bf16)fmaxf(u0.y + v0.y, 0.f);
                h0[2] = (__bf16)fmaxf(u0.z + v0.z, 0.f);
                h0[3] = (__bf16)fmaxf(u0.w + v0.w, 0.f);
                h0[4] = (__bf16)fmaxf(u1.x + v1.x, 0.f);
                h0[5] = (__bf16)fmaxf(u1.y + v1.y, 0.f);
                h0[6] = (__bf16)fmaxf(u1.z + v1.z, 0.f);
                h0[7] = (__bf16)fmaxf(u1.w + v1.w, 0.f);
                h1[0] = (__bf16)fmaxf(u2.x + v2.x, 0.f);
                h1[1] = (__bf16)fmaxf(u2.y + v2.y, 0.f);
                h1[2] = (__bf16)fmaxf(u2.z + v2.z, 0.f);
                h1[3] = (__bf16)fmaxf(u2.w + v2.w, 0.f);
                h1[4] = (__bf16)fmaxf(u3.x + v3.x, 0.f);
                h1[5] = (__bf16)fmaxf(u3.y + v3.y, 0.f);
                h1[6] = (__bf16)fmaxf(u3.z + v3.z, 0.f);
                h1[7] = (__bf16)fmaxf(u3.w + v3.w, 0.f);
                __bf16* w = &At[buf][woff];
                *(bf16x8*)w = h0;
                *(bf16x8*)(w + 128) = h1;
            };

            stage_B(0, 0);
            load_u(0);
            __syncthreads();           // v_a visible, Bt[0] DMA drained
            write_A(0, 0);
            __syncthreads();           // At[0] visible

            for (int kq = 0; kq < 16; ++kq) {
                const int buf = kq & 1;
                if (kq < 15) {
                    stage_B(buf ^ 1, kq + 1);
                    load_u(kq + 1);
                }
                bf16x8 af[4];
                #pragma unroll
                for (int mt = 0; mt < 4; ++mt)
                    af[mt] = *(const bf16x8*)&At[buf][(mtg + mt) * 512 + lane * 8];
                bf16x8 bfr[8];
                const __bf16* btb = &Bt[buf][(nloc + l15) * 32 + ((quad ^ swz) << 3)];
                #pragma unroll
                for (int nt = 0; nt < 8; ++nt)
                    bfr[nt] = *(const bf16x8*)(btb + nt * 512);
                #pragma unroll
                for (int mt = 0; mt < 4; ++mt)
                    #pragma unroll
                    for (int nt = 0; nt < 8; ++nt)
                        acc[mt][nt] = __builtin_amdgcn_mfma_f32_16x16x32_bf16(
                            af[mt], bfr[nt], acc[mt][nt], 0, 0, 0);
                if (kq < 15) write_A(buf ^ 1, kq + 1);
                __syncthreads();
            }

            #pragma unroll
            for (int nt = 0; nt < 8; ++nt) {
                const float q = qterm[b * G1_ + nbase + nloc + nt * 16 + l15];
                float s = 0.f;
                #pragma unroll
                for (int mt = 0; mt < 4; ++mt)
                    #pragma unroll
                    for (int r = 0; r < 4; ++r)
                        s += fmaxf(acc[mt][nt][r] + q, 0.f);
                s += __shfl_xor(s, 16, 64);
                s += __shfl_xor(s, 32, 64);
                if (quad == 0) ebuf[wave][nt * 16 + l15] = s;
            }
            __syncthreads();
            {
                const int grp = t >> 7, nl = t & 127;
                atomicAdd(xg + b * G1_ + nbase + grp * 128 + nl,
                          ebuf[grp * 2][nl] + ebuf[grp * 2 + 1][nl]);
            }
        }
    }
    gbar(bar, nblk);

    // ---------------- Phase 2: f1 + f2 (even blocks, 1/CU) ----------------
    if (!(blk & 1)) {
        const int id = blk >> 1;               // [0,256)
        const int b = id >> 5, og = id & 31;
        float* xs  = reinterpret_cast<float*>(&At[0][0]);   // 512
        float* s1  = xs + 512;                               // 512
        float* red = reinterpret_cast<float*>(&Bt[0][0]);    // 8*33
        xs[t] = xg[b * G1_ + t];
        xs[t + 256] = xg[b * G1_ + 256 + t];
        __syncthreads();
        {
            float a0 = f1b[t], a1 = f1b[t + 256];
            #pragma unroll 8
            for (int k = 0; k < G1_; ++k) {
                const float xv = xs[k];
                a0 += xv * f1w[k * F1_ + t];
                a1 += xv * f1w[k * F1_ + t + 256];
            }
            s1[t] = fmaxf(a0, 0.f);
            s1[t + 256] = fmaxf(a1, 0.f);
        }
        __syncthreads();
        {
            const int o = og * 32 + (t & 31), ks = (t >> 5) * 64;
            float s = 0.f;
            #pragma unroll 8
            for (int j = 0; j < 64; ++j)
                s += s1[ks + j] * f2w[(ks + j) * F2_ + o];
            red[(t >> 5) * 33 + (t & 31)] = s;
        }
        __syncthreads();
        if (t < 32) {
            float a = f2b[og * 32 + t];
            #pragma unroll
            for (int i = 0; i < 8; ++i) a += red[i * 33 + t];
            s2g[b * F2_ + og * 32 + t] = fmaxf(a, 0.f);
        }
    }
    gbar(bar, nblk);

    // ---------------- Phase 3: f3 + log_softmax (8 spread blocks) ----------
    if (!(blk & 63)) {
        const int b = blk >> 6;
        float* s2  = reinterpret_cast<float*>(&At[0][0]);   // 1024
        float* red = reinterpret_cast<float*>(&Bt[0][0]);    // 16*17
        float* lg  = &ebuf[0][0];                            // 16
        #pragma unroll
        for (int i = 0; i < 4; ++i) s2[t + i * 256] = s2g[b * F2_ + t + i * 256];
        __syncthreads();
        {
            const int o = t & 15, ks = (t >> 4) * 64;
            float a = 0.f;
            #pragma unroll 8
            for (int j = 0; j < 64; ++j)
                a += s2[ks + j] * f3w[(ks + j) * OUT_ + o];
            red[(t >> 4) * 17 + o] = a;
        }
        __syncthreads();
        if (t < 16) {
            float a = f3b[t];
            #pragma unroll
            for (int i = 0; i < 16; ++i) a += red[i * 17 + t];
            lg[t] = a;
        }
        __syncthreads();
        if (t < 16) {
            float m = -1e30f;
            #pragma unroll
            for (int i = 0; i < 16; ++i) m = fmaxf(m, lg[i]);
            float se = 0.f;
            #pragma unroll
            for (int i = 0; i < 16; ++i) se += __expf(lg[i] - m);
            out[b * OUT_ + t] = lg[t] - m - logf(se);
        }
    }
}

// ---------------------------------------------------------------------------
extern "C" void kernel_launch(void* const* d_in, const int* in_sizes, int n_in,
                              void* d_out, int out_size, void* d_ws, size_t ws_size,
                              hipStream_t stream) {
    const float* x   = (const float*)d_in[0];
    const float* qst = (const float*)d_in[1];
    const float* g0w = (const float*)d_in[2];
    const float* g0b = (const float*)d_in[3];
    const float* g1w = (const float*)d_in[4];
    const float* g1b = (const float*)d_in[5];
    const float* f1w = (const float*)d_in[6];
    const float* f1b = (const float*)d_in[7];
    const float* f2w = (const float*)d_in[8];
    const float* f2b = (const float*)d_in[9];
    const float* f3w = (const float*)d_in[10];
    const float* f3b = (const float*)d_in[11];

    char* ws = (char*)d_ws;
    float*  u     = (float*)ws;  ws += (size_t)B_ * D_ * G0P * 4;   // 2 MB
    float*  v     = (float*)ws;  ws += (size_t)B_ * D_ * G0P * 4;   // 2 MB
    __bf16* w1t   = (__bf16*)ws; ws += (size_t)G1_ * G0P * 2;       // 512 KB
    float*  qterm = (float*)ws;  ws += (size_t)B_ * G1_ * 4;
    float*  xg    = (float*)ws;  ws += (size_t)B_ * G1_ * 4;
    float*  s2g   = (float*)ws;  ws += (size_t)B_ * F2_ * 4;
    int*    bar   = (int*)ws;    ws += 256;

    hipMemsetAsync(bar, 0, 8, stream);
    k_prep<<<1320, 256, 0, stream>>>(x, g0w, g0b, qst, g1w, g1b,
                                     u, v, w1t, qterm, xg);
    k_main<<<512, 256, 0, stream>>>(u, v, w1t, qterm,
                                    f1w, f1b, f2w, f2b, f3w, f3b,
                                    xg, s2g, (float*)d_out, bar);
}

// Round 11
// 252.723 us; speedup vs baseline: 1.3751x; 1.3751x over previous
//
#include <hip/hip_runtime.h>
#include <hip/hip_bf16.h>

#define B_  8
#define D_  128
#define K_  7
#define Q_  256
#define G0_ 511
#define G0P 512
#define G1_ 512
#define F1_ 512
#define F2_ 1024
#define OUT_ 16

typedef __bf16 bf16x8 __attribute__((ext_vector_type(8)));
typedef float  f32x4  __attribute__((ext_vector_type(4)));

// async global->LDS: one instruction = 64 lanes x 16B = 1KB.
#define GL2LDS(g, l) __builtin_amdgcn_global_load_lds(                        \
    (const __attribute__((address_space(1))) void*)(g),                       \
    (__attribute__((address_space(3))) void*)(l), 16, 0, 0)

// ---------------------------------------------------------------------------
// Device-scope generation barrier (HW-validated in R10). bar[0]=count, bar[1]=gen.
__device__ __forceinline__ void gbar(int* bar, int nblk) {
    __syncthreads();
    if (threadIdx.x == 0) {
        __threadfence();
        const int g = __hip_atomic_load(&bar[1], __ATOMIC_ACQUIRE,
                                        __HIP_MEMORY_SCOPE_AGENT);
        const int prev = __hip_atomic_fetch_add(&bar[0], 1, __ATOMIC_ACQ_REL,
                                                __HIP_MEMORY_SCOPE_AGENT);
        if (prev == nblk - 1) {
            __hip_atomic_store(&bar[0], 0, __ATOMIC_RELAXED,
                               __HIP_MEMORY_SCOPE_AGENT);
            __hip_atomic_fetch_add(&bar[1], 1, __ATOMIC_RELEASE,
                                   __HIP_MEMORY_SCOPE_AGENT);
        } else {
            while (__hip_atomic_load(&bar[1], __ATOMIC_ACQUIRE,
                                     __HIP_MEMORY_SCOPE_AGENT) == g)
                __builtin_amdgcn_s_sleep(2);
        }
        __threadfence();
    }
    __syncthreads();
}

// ---------------------------------------------------------------------------
// k_prep: fused preprocessing, 2092 blocks x 256 threads (R6-verified), plus
// zeroing the tail barrier (replaces the memset dispatch).
//  [0,1024):      u/v rows
//  [1024,1280):   w1 -> swizzled bf16 w1t
//  [1280,1312):   qterm
//  [1312,1320):   zero xg (+ blk 1319 zeroes bar)
//  [1320,1576):   f1w transpose -> f1t[o][k]
//  [1576,2088):   f2w transpose -> f2t[o][k]
//  [2088,2092):   f3w transpose -> f3t[o][k]
__global__ void k_prep(const float* __restrict__ x, const float* __restrict__ g0w,
                       const float* __restrict__ g0b, const float* __restrict__ qst,
                       const float* __restrict__ g1w, const float* __restrict__ g1b,
                       const float* __restrict__ f1w, const float* __restrict__ f2w,
                       const float* __restrict__ f3w,
                       float* __restrict__ u, float* __restrict__ v,
                       __bf16* __restrict__ w1t, float* __restrict__ qterm,
                       float* __restrict__ xg, float* __restrict__ f1t,
                       float* __restrict__ f2t, float* __restrict__ f3t,
                       int* __restrict__ bar) {
    const int blk = blockIdx.x;
    const int t   = threadIdx.x;
    if (blk < 1024) {
        __shared__ float xs[8];
        if (t < K_) xs[t] = x[blk * K_ + t];
        __syncthreads();
        #pragma unroll
        for (int h = 0; h < 2; ++h) {
            const int g = t + h * 256;
            float su = 0.f, sv = 0.f;
            if (g < G0_) {
                #pragma unroll
                for (int k = 0; k < K_; ++k) {
                    su += xs[k] * g0w[k * G0_ + g];
                    sv += xs[k] * g0w[(K_ + k) * G0_ + g];
                }
                su += g0b[g];
            }
            u[blk * G0P + g] = (g < G0_) ? su : 0.f;
            v[blk * G0P + g] = (g < G0_) ? sv : 0.f;
        }
    } else if (blk < 1280) {
        __shared__ __bf16 tile[32][33];
        const int bb = blk - 1024;
        const int bx = bb & 15, by = bb >> 4;
        const int r = t >> 5, c = t & 31;
        #pragma unroll
        for (int i = 0; i < 4; ++i) {
            const int k = by * 32 + r + i * 8;
            const int n = bx * 32 + c;
            tile[r + i * 8][c] = (__bf16)((k < G0_) ? g1w[k * G1_ + n] : 0.f);
        }
        __syncthreads();
        #pragma unroll
        for (int i = 0; i < 4; ++i) {
            const int n = bx * 32 + r + i * 8;
            const int cc = (c >> 3) & 3, j = c & 7;
            const int slot = cc ^ ((n >> 1) & 3);
            w1t[by * 16384 + n * 32 + slot * 8 + j] = tile[c][r + i * 8];
        }
    } else if (blk < 1312) {
        __shared__ float qs[256];
        __shared__ float red[2][128];
        const int qb = blk - 1280;
        const int b = qb >> 2, nb = (qb & 3) << 7;
        qs[t] = qst[b * Q_ + t];
        __syncthreads();
        const int n = nb + (t & 127);
        const int qh = (t >> 7) * 128;
        float s = 0.f;
        #pragma unroll 8
        for (int q = 0; q < 128; ++q)
            s += qs[qh + q] * g1w[(G0_ + qh + q) * G1_ + n];
        red[t >> 7][t & 127] = s;
        __syncthreads();
        if (t < 128)
            qterm[b * G1_ + nb + t] = red[0][t] + red[1][t] + g1b[nb + t];
    } else if (blk < 1320) {
        const int b = blk - 1312;
        xg[b * G1_ + t] = 0.f;
        xg[b * G1_ + 256 + t] = 0.f;
        if (blk == 1319 && t < 8) bar[t] = 0;
    } else if (blk < 1576) {
        __shared__ float tile[32][33];
        const int j = blk - 1320;
        const int bo = j & 15, bk = j >> 4;
        const int r = t >> 5, c = t & 31;
        #pragma unroll
        for (int i = 0; i < 4; ++i)
            tile[r + i * 8][c] = f1w[(bk * 32 + r + i * 8) * F1_ + bo * 32 + c];
        __syncthreads();
        #pragma unroll
        for (int i = 0; i < 4; ++i)
            f1t[(bo * 32 + r + i * 8) * G1_ + bk * 32 + c] = tile[c][r + i * 8];
    } else if (blk < 2088) {
        __shared__ float tile[32][33];
        const int j = blk - 1576;
        const int bo = j & 31, bk = j >> 5;
        const int r = t >> 5, c = t & 31;
        #pragma unroll
        for (int i = 0; i < 4; ++i)
            tile[r + i * 8][c] = f2w[(bk * 32 + r + i * 8) * F2_ + bo * 32 + c];
        __syncthreads();
        #pragma unroll
        for (int i = 0; i < 4; ++i)
            f2t[(bo * 32 + r + i * 8) * F1_ + bk * 32 + c] = tile[c][r + i * 8];
    } else {
        const int k = (blk - 2088) * 256 + t;
        float4 r0 = *(const float4*)(f3w + k * OUT_);
        float4 r1 = *(const float4*)(f3w + k * OUT_ + 4);
        float4 r2 = *(const float4*)(f3w + k * OUT_ + 8);
        float4 r3 = *(const float4*)(f3w + k * OUT_ + 12);
        const float rr[16] = {r0.x,r0.y,r0.z,r0.w, r1.x,r1.y,r1.z,r1.w,
                              r2.x,r2.y,r2.z,r2.w, r3.x,r3.y,r3.z,r3.w};
        #pragma unroll
        for (int o = 0; o < 16; ++o) f3t[o * F2_ + k] = rr[o];
    }
}

// ---------------------------------------------------------------------------
// k_pair: R3-VERIFIED core, untouched. block = (b, a, nhalf). M=128,N=256,K=512.
__global__ __launch_bounds__(256, 2)
void k_pair(const float* __restrict__ u, const float* __restrict__ v,
            const __bf16* __restrict__ w1t, const float* __restrict__ qterm,
            float* __restrict__ xg) {
    __shared__ float  v_a[512];
    __shared__ __bf16 At[2][4096];
    __shared__ __bf16 Bt[2][8192];
    __shared__ float  ebuf[4][128];

    const int bid  = blockIdx.x;
    const int b    = bid >> 8;
    const int a    = (bid >> 1) & 127;
    const int nbase = (bid & 1) << 8;
    const int tid  = threadIdx.x;
    const int wave = tid >> 6, lane = tid & 63;
    const int quad = lane >> 4, l15 = lane & 15;
    const int nloc = (wave >> 1) * 128;
    const int mtg  = (wave & 1) * 4;
    const int swz  = (l15 >> 1) & 3;

    if (tid < 128)
        *(float4*)(v_a + tid * 4) = *(const float4*)(v + (b * D_ + a) * G0P + tid * 4);

    const int iw0 = wave * 4;
    const __bf16* gsrc = w1t + (size_t)(nbase + iw0 * 16 + (lane >> 2)) * 32
                             + (lane & 3) * 8;

    const int sm = tid >> 1;
    const int sk = (tid & 1) << 4;
    const float* urow = u + (b * D_ + sm) * G0P + sk;
    const int woff = (sm >> 4) * 512 + (sk >> 3) * 128 + (sm & 15) * 8;

    f32x4 acc[4][8];
    #pragma unroll
    for (int mt = 0; mt < 4; ++mt)
        #pragma unroll
        for (int nt = 0; nt < 8; ++nt)
            acc[mt][nt] = (f32x4){0.f, 0.f, 0.f, 0.f};

    float4 u0, u1, u2, u3;
    auto load_u = [&](int kq) {
        const float* p = urow + kq * 32;
        u0 = *(const float4*)p;       u1 = *(const float4*)(p + 4);
        u2 = *(const float4*)(p + 8); u3 = *(const float4*)(p + 12);
    };
    auto stage_B = [&](int buf, int kq) {
        const __bf16* g = gsrc + kq * 16384;
        __bf16* l = &Bt[buf][iw0 * 512];
        #pragma unroll
        for (int j = 0; j < 4; ++j)
            GL2LDS(g + j * 512, l + j * 512);
    };
    auto write_A = [&](int buf, int kq) {
        const float* vp = v_a + kq * 32 + sk;
        const float4 v0 = *(const float4*)vp,       v1 = *(const float4*)(vp + 4);
        const float4 v2 = *(const float4*)(vp + 8), v3 = *(const float4*)(vp + 12);
        bf16x8 h0, h1;
        h0[0] = (__bf16)fmaxf(u0.x + v0.x, 0.f);
        h0[1] = (__bf16)fmaxf(u0.y + v0.y, 0.f);
        h0[2] = (__bf16)fmaxf(u0.z + v0.z, 0.f);
        h0[3] = (__bf16)fmaxf(u0.w + v0.w, 0.f);
        h0[4] = (__bf16)fmaxf(u1.x + v1.x, 0.f);
        h0[5] = (__bf16)fmaxf(u1.y + v1.y, 0.f);
        h0[6] = (__bf16)fmaxf(u1.z + v1.z, 0.f);
        h0[7] = (__bf16)fmaxf(u1.w + v1.w, 0.f);
        h1[0] = (__bf16)fmaxf(u2.x + v2.x, 0.f);
        h1[1] = (__bf16)fmaxf(u2.y + v2.y, 0.f);
        h1[2] = (__bf16)fmaxf(u2.z + v2.z, 0.f);
        h1[3] = (__bf16)fmaxf(u2.w + v2.w, 0.f);
        h1[4] = (__bf16)fmaxf(u3.x + v3.x, 0.f);
        h1[5] = (__bf16)fmaxf(u3.y + v3.y, 0.f);
        h1[6] = (__bf16)fmaxf(u3.z + v3.z, 0.f);
        h1[7] = (__bf16)fmaxf(u3.w + v3.w, 0.f);
        __bf16* w = &At[buf][woff];
        *(bf16x8*)w = h0;
        *(bf16x8*)(w + 128) = h1;
    };

    stage_B(0, 0);
    load_u(0);
    __syncthreads();
    write_A(0, 0);
    __syncthreads();

    for (int kq = 0; kq < 16; ++kq) {
        const int buf = kq & 1;
        if (kq < 15) {
            stage_B(buf ^ 1, kq + 1);
            load_u(kq + 1);
        }
        bf16x8 af[4];
        #pragma unroll
        for (int mt = 0; mt < 4; ++mt)
            af[mt] = *(const bf16x8*)&At[buf][(mtg + mt) * 512 + lane * 8];
        bf16x8 bfr[8];
        const __bf16* btb = &Bt[buf][(nloc + l15) * 32 + ((quad ^ swz) << 3)];
        #pragma unroll
        for (int nt = 0; nt < 8; ++nt)
            bfr[nt] = *(const bf16x8*)(btb + nt * 512);
        #pragma unroll
        for (int mt = 0; mt < 4; ++mt)
            #pragma unroll
            for (int nt = 0; nt < 8; ++nt)
                acc[mt][nt] = __builtin_amdgcn_mfma_f32_16x16x32_bf16(
                    af[mt], bfr[nt], acc[mt][nt], 0, 0, 0);
        if (kq < 15) write_A(buf ^ 1, kq + 1);
        __syncthreads();
    }

    #pragma unroll
    for (int nt = 0; nt < 8; ++nt) {
        const float q = qterm[b * G1_ + nbase + nloc + nt * 16 + l15];
        float s = 0.f;
        #pragma unroll
        for (int mt = 0; mt < 4; ++mt)
            #pragma unroll
            for (int r = 0; r < 4; ++r)
                s += fmaxf(acc[mt][nt][r] + q, 0.f);
        s += __shfl_xor(s, 16, 64);
        s += __shfl_xor(s, 32, 64);
        if (quad == 0) ebuf[wave][nt * 16 + l15] = s;
    }
    __syncthreads();
    {
        const int grp = tid >> 7, nl = tid & 127;
        atomicAdd(xg + b * G1_ + nbase + grp * 128 + nl,
                  ebuf[grp * 2][nl] + ebuf[grp * 2 + 1][nl]);
    }
}

// ---------------------------------------------------------------------------
// k_tail: entire f-MLP + log_softmax in ONE dispatch, 256 blocks x 256 threads.
// Phase A: f1 (1024 waves x 4 dots)  -> gbar -> Phase B: f2 (x 8 dots)
// -> gbar -> Phase C: f3+softmax on blocks blk%32==0. Wave-per-dot code is
// R6-verified; co-residency of 256 blocks is capacity-guaranteed.
__global__ __launch_bounds__(256)
void k_tail(const float* __restrict__ xg,  const float* __restrict__ f1t,
            const float* __restrict__ f1b, const float* __restrict__ f2t,
            const float* __restrict__ f2b, const float* __restrict__ f3t,
            const float* __restrict__ f3b, float* __restrict__ s1g,
            float* __restrict__ s2g, float* __restrict__ out,
            int* __restrict__ bar) {
    const int blk = blockIdx.x, t = threadIdx.x;
    const int wave = t >> 6, lane = t & 63;
    const int w = blk * 4 + wave;          // global wave id [0,1024)

    // ---- Phase A: f1 (4096 dots; wave w -> dots w*4..w*4+3, same b) ----
    {
        const int b = (w * 4) >> 9;
        const float* xr = xg + b * G1_ + lane * 8;
        const float4 a0 = *(const float4*)xr, a1 = *(const float4*)(xr + 4);
        #pragma unroll
        for (int j = 0; j < 4; ++j) {
            const int oo = (w * 4 + j) & 511;
            const float* wr = f1t + oo * G1_ + lane * 8;
            const float4 b0 = *(const float4*)wr, b1 = *(const float4*)(wr + 4);
            float s = a0.x*b0.x + a0.y*b0.y + a0.z*b0.z + a0.w*b0.w
                    + a1.x*b1.x + a1.y*b1.y + a1.z*b1.z + a1.w*b1.w;
            #pragma unroll
            for (int off = 32; off >= 1; off >>= 1) s += __shfl_xor(s, off, 64);
            if (lane == 0) s1g[b * F1_ + oo] = fmaxf(s + f1b[oo], 0.f);
        }
    }
    gbar(bar, 256);

    // ---- Phase B: f2 (8192 dots; wave w -> dots w*8..w*8+7, same b) ----
    {
        const int b = (w * 8) >> 10;
        const float* xr = s1g + b * F1_ + lane * 8;
        const float4 a0 = *(const float4*)xr, a1 = *(const float4*)(xr + 4);
        #pragma unroll
        for (int j = 0; j < 8; ++j) {
            const int oo = (w * 8 + j) & 1023;
            const float* wr = f2t + oo * F1_ + lane * 8;
            const float4 b0 = *(const float4*)wr, b1 = *(const float4*)(wr + 4);
            float s = a0.x*b0.x + a0.y*b0.y + a0.z*b0.z + a0.w*b0.w
                    + a1.x*b1.x + a1.y*b1.y + a1.z*b1.z + a1.w*b1.w;
            #pragma unroll
            for (int off = 32; off >= 1; off >>= 1) s += __shfl_xor(s, off, 64);
            if (lane == 0) s2g[b * F2_ + oo] = fmaxf(s + f2b[oo], 0.f);
        }
    }
    gbar(bar, 256);

    // ---- Phase C: f3 + log_softmax (8 blocks) — R6-verified k_f3 body ----
    if (!(blk & 31)) {
        const int b = blk >> 5;
        __shared__ float lg[16];
        float4 xs[4];
        #pragma unroll
        for (int j = 0; j < 4; ++j)
            xs[j] = *(const float4*)(s2g + b * F2_ + lane * 16 + j * 4);
        #pragma unroll
        for (int oi = 0; oi < 4; ++oi) {
            const int o = wave * 4 + oi;
            const float* wr = f3t + o * F2_ + lane * 16;
            float s = 0.f;
            #pragma unroll
            for (int j = 0; j < 4; ++j) {
                const float4 ww = *(const float4*)(wr + j * 4);
                s += xs[j].x*ww.x + xs[j].y*ww.y + xs[j].z*ww.z + xs[j].w*ww.w;
            }
            #pragma unroll
            for (int off = 32; off >= 1; off >>= 1) s += __shfl_xor(s, off, 64);
            if (lane == 0) lg[o] = s + f3b[o];
        }
        __syncthreads();
        if (t < 16) {
            float m = -1e30f;
            #pragma unroll
            for (int i = 0; i < 16; ++i) m = fmaxf(m, lg[i]);
            float se = 0.f;
            #pragma unroll
            for (int i = 0; i < 16; ++i) se += __expf(lg[i] - m);
            out[b * OUT_ + t] = lg[t] - m - logf(se);
        }
    }
}

// ---------------------------------------------------------------------------
extern "C" void kernel_launch(void* const* d_in, const int* in_sizes, int n_in,
                              void* d_out, int out_size, void* d_ws, size_t ws_size,
                              hipStream_t stream) {
    const float* x   = (const float*)d_in[0];
    const float* qst = (const float*)d_in[1];
    const float* g0w = (const float*)d_in[2];
    const float* g0b = (const float*)d_in[3];
    const float* g1w = (const float*)d_in[4];
    const float* g1b = (const float*)d_in[5];
    const float* f1w = (const float*)d_in[6];
    const float* f1b = (const float*)d_in[7];
    const float* f2w = (const float*)d_in[8];
    const float* f2b = (const float*)d_in[9];
    const float* f3w = (const float*)d_in[10];
    const float* f3b = (const float*)d_in[11];

    char* ws = (char*)d_ws;
    float*  u     = (float*)ws;  ws += (size_t)B_ * D_ * G0P * 4;   // 2 MB
    float*  v     = (float*)ws;  ws += (size_t)B_ * D_ * G0P * 4;   // 2 MB
    __bf16* w1t   = (__bf16*)ws; ws += (size_t)G1_ * G0P * 2;       // 512 KB
    float*  qterm = (float*)ws;  ws += (size_t)B_ * G1_ * 4;
    float*  xg    = (float*)ws;  ws += (size_t)B_ * G1_ * 4;
    float*  s1g   = (float*)ws;  ws += (size_t)B_ * F1_ * 4;
    float*  s2g   = (float*)ws;  ws += (size_t)B_ * F2_ * 4;
    float*  f1t   = (float*)ws;  ws += (size_t)F1_ * G1_ * 4;       // 1 MB
    float*  f2t   = (float*)ws;  ws += (size_t)F2_ * F1_ * 4;       // 2 MB
    float*  f3t   = (float*)ws;  ws += (size_t)OUT_ * F2_ * 4;      // 64 KB
    int*    bar   = (int*)ws;    ws += 256;

    k_prep<<<2092, 256, 0, stream>>>(x, g0w, g0b, qst, g1w, g1b, f1w, f2w, f3w,
                                     u, v, w1t, qterm, xg, f1t, f2t, f3t, bar);
    k_pair<<<B_ * D_ * 2, 256, 0, stream>>>(u, v, w1t, qterm, xg);
    k_tail<<<256, 256, 0, stream>>>(xg, f1t, f1b, f2t, f2b, f3t, f3b,
                                    s1g, s2g, (float*)d_out, bar);
}